// Round 3
// baseline (370.863 us; speedup 1.0000x reference)
//
#include <hip/hip_runtime.h>
#include <math.h>

#define DIMC 1024
#define SEQ 4096
#define BATCH 4
#define NH 16
#define HD 64
#define MTOT (BATCH * SEQ)      // 16384 rows
#define NSPLIT 8
#define PELEMS (64 * 64 * 64 + 64 * 64)   // KV partial + Z partial per split
#define EPS 1e-6f

typedef __bf16 bf16x8 __attribute__((ext_vector_type(8)));
typedef __bf16 bf16x4 __attribute__((ext_vector_type(4)));
typedef __bf16 bf16x2 __attribute__((ext_vector_type(2)));
typedef float  f32x4  __attribute__((ext_vector_type(4)));

#define MFMA16 __builtin_amdgcn_mfma_f32_16x16x32_bf16

__device__ __forceinline__ float phi_f(float x) {
    return x > 0.0f ? x + 1.0f : __expf(x);   // elu(x)+1
}

// ---------------------------------------------------------------------------
// One-shot fp32->bf16 conversion of x + all 4 weight matrices.
// ---------------------------------------------------------------------------
__global__ __launch_bounds__(256) void cvt_all(
    const float* __restrict__ x,
    const float* __restrict__ Wq, const float* __restrict__ Wk,
    const float* __restrict__ Wv, const float* __restrict__ Wo,
    __bf16* __restrict__ xb,
    __bf16* __restrict__ Wqb, __bf16* __restrict__ Wkb,
    __bf16* __restrict__ Wvb, __bf16* __restrict__ Wob)
{
    const size_t big = (size_t)MTOT * DIMC;
    const size_t wsz = (size_t)DIMC * DIMC;
    size_t i = ((size_t)blockIdx.x * 256 + threadIdx.x) * 4;
    const float* src; __bf16* dst; size_t off;
    if (i < big) { src = x; dst = xb; off = i; }
    else {
        size_t j = i - big;
        int w = (int)(j >> 20);            // /wsz (2^20)
        off = j & (wsz - 1);
        switch (w) {
            case 0: src = Wq; dst = Wqb; break;
            case 1: src = Wk; dst = Wkb; break;
            case 2: src = Wv; dst = Wvb; break;
            default: src = Wo; dst = Wob; break;
        }
    }
    float4 v = *(const float4*)(src + off);
    bf16x4 o = { (__bf16)v.x, (__bf16)v.y, (__bf16)v.z, (__bf16)v.w };
    *(bf16x4*)(dst + off) = o;
}

// ---------------------------------------------------------------------------
// Persistent 256x256 8-wave BK=64 GEMM panel, 8-phase schedule, counted vmcnt
// (T2+T3+T4+T5). NMAT=3 fuses Q/K/V: one block owns one (m,n) panel and runs
// a CONTINUOUS 48-K-tile loop (16 per matrix). The A(X) staging k-index wraps
// naturally ((t+1)&15); the B source switches W matrices via (t+2)>>4; the
// pipeline never drains across matrix boundaries. Per-matrix epilogue is
// injected in-loop at (t&15)==15. 256 blocks = exactly 1/CU = ONE round
// (R1 post-mortem: 768-block/3-round version paid 3x prologue+epilogue+tail).
//
// LDS: 2 buf x {A,B} x 2 row-halves x [128][64] bf16 = 128 KiB.
// Swizzle: linear global_load_lds dest + pre-swizzled GLOBAL source column
// block (blk ^= row&7) + same XOR on ds_read (rule #21). R1 measured:
// SQ_LDS_BANK_CONFLICT 1.26e7 -> 0.
//
// Epilogue stores j-INNERMOST so each 16-lane quad completes its 128B line in
// 4 consecutive stores (R1: j-outer left lines open ~32 insts -> partial-line
// evictions -> WRITE_SIZE 2x ideal). Epilogue stores enter the vmcnt queue
// OLDER than the next tile's staged loads, so the counted vmcnt(6) at the
// following ph4 still leaves exactly tile t+2's 3 half-tiles in flight.
// ---------------------------------------------------------------------------
template<int NMAT, int OUT_BF16>
__device__ __forceinline__ void gemm_persist(
    const __bf16* __restrict__ X,
    const __bf16* __restrict__ W0, const __bf16* __restrict__ W1,
    const __bf16* __restrict__ W2,
    const float* __restrict__ bias0, const float* __restrict__ bias1,
    const float* __restrict__ bias2,
    void* __restrict__ Y0, void* __restrict__ Y1, void* __restrict__ Y2,
    int m0, int n0)
{
    constexpr int TNKT = NMAT * 16;
    __shared__ __attribute__((aligned(16))) __bf16 lds[65536]; // 128 KiB
    const int tid  = threadIdx.x;
    const int wave = tid >> 6, lane = tid & 63;
    const int wm = wave >> 2, wn = wave & 3;          // 2 x 4 wave grid
    const int fr = lane & 15, fkb = lane >> 4;        // fragment row / k-block
    const int fsw = fr & 7;                           // read-side XOR swizzle
    const int srow = lane >> 3;                       // staging row in 8-group
    const int sblk = (lane & 7) ^ srow;               // pre-swizzled src block

    const size_t aoff = (size_t)(m0 + wave * 8 + srow) * DIMC + sblk * 8;
    const size_t boff = (size_t)(n0 + wave * 8 + srow) * DIMC + sblk * 8;
    const __bf16* Asrc = X + aoff;
    const __bf16* Bs0 = W0 + boff;
    const __bf16* Bs1 = W1 + boff;
    const __bf16* Bs2 = W2 + boff;
    __bf16* lw = lds + wave * 512;   // wave's 8-row slice in each 64-row block

    auto bsel = [&](int t) -> const __bf16* {
        if (NMAT == 1) return Bs0;
        const int mat = t >> 4;
        return mat == 0 ? Bs0 : (mat == 1 ? Bs1 : Bs2);
    };
    auto stage = [&](const __bf16* base, int h, int kblk, int isB, int bb) {
        const __bf16* s = base + (size_t)(h * 128) * DIMC + (size_t)kblk * 64;
        __bf16* d = lw + bb * 32768 + isB * 16384 + h * 8192;
        #pragma unroll
        for (int g = 0; g < 2; ++g)
            __builtin_amdgcn_global_load_lds(
                (const __attribute__((address_space(1))) void*)(s + (size_t)g * 64 * DIMC),
                (__attribute__((address_space(3))) void*)(d + g * 4096),
                16, 0, 0);
    };
    // A frag: rows wm*128 + i*16 + fr, k = ks*32 + fkb*8 (block XOR-swizzled)
    auto lda = [&](int bb, int i, int ks) -> bf16x8 {
        return *(const bf16x8*)(lds + bb * 32768 + wm * 8192
                 + (i * 16 + fr) * 64 + (((ks * 4 + fkb) ^ fsw) * 8));
    };
    // B frag: rows wn*64 + j*16 + fr  (half = wn>>1, local row = (wn&1)*64+..)
    auto ldb = [&](int bb, int j, int ks) -> bf16x8 {
        return *(const bf16x8*)(lds + bb * 32768 + 16384 + (wn >> 1) * 8192
                 + ((wn & 1) * 64 + j * 16 + fr) * 64 + (((ks * 4 + fkb) ^ fsw) * 8));
    };

    f32x4 acc[8][4] = {};
    bf16x8 a[4][2], b[4][2];

    // prologue: tile0 {B0,B1,A0,A1} + tile1 {B0,B1,A0}; A1(1) issued in ph1(0)
    stage(Bs0, 0, 0, 1, 0); stage(Bs0, 1, 0, 1, 0);
    stage(Asrc, 0, 0, 0, 0); stage(Asrc, 1, 0, 0, 0);
    stage(Bs0, 0, 1, 1, 1); stage(Bs0, 1, 1, 1, 1);
    stage(Asrc, 0, 1, 0, 1);
    asm volatile("s_waitcnt vmcnt(6)" ::: "memory");   // tile 0 resident
    __builtin_amdgcn_s_barrier();

    #pragma unroll 2
    for (int t = 0; t < TNKT; ++t) {
        const int buf = t & 1;
        // ---- phase 1: A frags 0-3, B frags 0-1; stage A-h1(t+1)
        #pragma unroll
        for (int i = 0; i < 4; ++i)
            #pragma unroll
            for (int ks = 0; ks < 2; ++ks) a[i][ks] = lda(buf, i, ks);
        #pragma unroll
        for (int j = 0; j < 2; ++j)
            #pragma unroll
            for (int ks = 0; ks < 2; ++ks) b[j][ks] = ldb(buf, j, ks);
        if (t + 1 < TNKT) stage(Asrc, 1, (t + 1) & 15, 0, buf ^ 1);
        __builtin_amdgcn_s_barrier();
        asm volatile("s_waitcnt lgkmcnt(0)" ::: "memory");
        __builtin_amdgcn_s_setprio(1);
        #pragma unroll
        for (int i = 0; i < 4; ++i)
            #pragma unroll
            for (int j = 0; j < 2; ++j)
                #pragma unroll
                for (int ks = 0; ks < 2; ++ks)
                    acc[i][j] = MFMA16(a[i][ks], b[j][ks], acc[i][j], 0, 0, 0);
        __builtin_amdgcn_s_setprio(0);
        __builtin_amdgcn_s_barrier();
        // ---- phase 2: B frags 2-3
        #pragma unroll
        for (int j = 2; j < 4; ++j)
            #pragma unroll
            for (int ks = 0; ks < 2; ++ks) b[j][ks] = ldb(buf, j, ks);
        __builtin_amdgcn_s_barrier();
        asm volatile("s_waitcnt lgkmcnt(0)" ::: "memory");
        __builtin_amdgcn_s_setprio(1);
        #pragma unroll
        for (int i = 0; i < 4; ++i)
            #pragma unroll
            for (int j = 2; j < 4; ++j)
                #pragma unroll
                for (int ks = 0; ks < 2; ++ks)
                    acc[i][j] = MFMA16(a[i][ks], b[j][ks], acc[i][j], 0, 0, 0);
        __builtin_amdgcn_s_setprio(0);
        __builtin_amdgcn_s_barrier();
        // ---- phase 3: A frags 4-7; stage B-h0(t+2)
        #pragma unroll
        for (int i = 0; i < 4; ++i)
            #pragma unroll
            for (int ks = 0; ks < 2; ++ks) a[i][ks] = lda(buf, i + 4, ks);
        if (t + 2 < TNKT) stage(bsel(t + 2), 0, (t + 2) & 15, 1, buf);
        __builtin_amdgcn_s_barrier();
        asm volatile("s_waitcnt lgkmcnt(0)" ::: "memory");
        __builtin_amdgcn_s_setprio(1);
        #pragma unroll
        for (int i = 0; i < 4; ++i)
            #pragma unroll
            for (int j = 2; j < 4; ++j)
                #pragma unroll
                for (int ks = 0; ks < 2; ++ks)
                    acc[i + 4][j] = MFMA16(a[i][ks], b[j][ks], acc[i + 4][j], 0, 0, 0);
        __builtin_amdgcn_s_setprio(0);
        __builtin_amdgcn_s_barrier();
        // ---- phase 4: stage B-h1(t+2), A-h0(t+2); reg-only MFMA; counted vmcnt
        if (t + 2 < TNKT) {
            stage(bsel(t + 2), 1, (t + 2) & 15, 1, buf);
            stage(Asrc, 0, (t + 2) & 15, 0, buf);
        }
        __builtin_amdgcn_s_setprio(1);
        #pragma unroll
        for (int i = 0; i < 4; ++i)
            #pragma unroll
            for (int j = 0; j < 2; ++j)
                #pragma unroll
                for (int ks = 0; ks < 2; ++ks)
                    acc[i + 4][j] = MFMA16(a[i][ks], b[j][ks], acc[i + 4][j], 0, 0, 0);
        __builtin_amdgcn_s_setprio(0);
        if (t < TNKT - 2)       asm volatile("s_waitcnt vmcnt(6)" ::: "memory");
        else if (t == TNKT - 2) asm volatile("s_waitcnt vmcnt(0)" ::: "memory");
        __builtin_amdgcn_s_barrier();

        // ---- in-loop epilogue every 16 K-tiles (one matrix done)
        if ((t & 15) == 15) {
            const int mat = (NMAT == 1) ? 0 : (t >> 4);
            const float* bias = (mat == 0) ? bias0 : (mat == 1) ? bias1 : bias2;
            void* Yv = (mat == 0) ? Y0 : (mat == 1) ? Y1 : Y2;
            const int col_l = lane & 15, quad = lane >> 4;
            const int cbase = n0 + wn * 64 + col_l;
            float bb[4];
            #pragma unroll
            for (int j = 0; j < 4; ++j) bb[j] = bias[cbase + j * 16];
            #pragma unroll
            for (int i = 0; i < 8; ++i) {
                #pragma unroll
                for (int r = 0; r < 4; ++r) {
                    const size_t grow = (size_t)(m0 + wm * 128 + i * 16 + quad * 4 + r) * DIMC;
                    #pragma unroll
                    for (int j = 0; j < 4; ++j) {   // j-inner: line closes fast
                        float v = acc[i][j][r] + bb[j];
                        if (NMAT == 3 && mat != 2) v = phi_f(v);
                        if (OUT_BF16)
                            ((__bf16*)Yv)[grow + cbase + j * 16] = (__bf16)v;
                        else
                            ((float*)Yv)[grow + cbase + j * 16] = v;
                        acc[i][j][r] = 0.0f;
                    }
                }
            }
        }
    }
}

// ---------------------------------------------------------------------------
// Fused persistent Q/K/V projection: 256 blocks = 64 m-panels x 4 n-panels,
// each runs the continuous 48-tile loop over {Wq,Wk,Wv}.
// ---------------------------------------------------------------------------
__global__ __launch_bounds__(512, 2) void gemm_qkv(
    const __bf16* __restrict__ X,
    const __bf16* __restrict__ Wq, const __bf16* __restrict__ Wk,
    const __bf16* __restrict__ Wv,
    const float* __restrict__ bq, const float* __restrict__ bk,
    const float* __restrict__ bv,
    __bf16* __restrict__ Q, __bf16* __restrict__ K, __bf16* __restrict__ V)
{
    const int l = blockIdx.x;
    const int xcd = l & 7, s = l >> 3;          // s in [0,32)
    const int m_idx = xcd * 8 + (s >> 2);
    const int nb = s & 3;
    gemm_persist<3, 1>(X, Wq, Wk, Wv, bq, bk, bv,
                       (void*)Q, (void*)K, (void*)V, m_idx * 256, nb * 256);
}

// ---------------------------------------------------------------------------
// Output projection: out = A @ Wo^T + bo (fp32 out). 256 blocks = 1/CU.
// ---------------------------------------------------------------------------
__global__ __launch_bounds__(512, 2) void gemm_out(
    const __bf16* __restrict__ A, const __bf16* __restrict__ Wo,
    const float* __restrict__ bo, float* __restrict__ out)
{
    const int l = blockIdx.x;
    const int xcd = l & 7, s = l >> 3;          // s in [0,32)
    const int m_idx = xcd * 8 + (s >> 2);
    const int nb = s & 3;
    gemm_persist<1, 0>(A, Wo, Wo, Wo, bo, bo, bo,
                       (void*)out, (void*)out, (void*)out,
                       m_idx * 256, nb * 256);
}

// ---------------------------------------------------------------------------
// Per (b,h,split): partial KV[d][e] = sum_n K[n,d]*V[n,e], partial Z[d].
// MFMA over LDS-transposed tiles; partials streamed, no global atomics.
// ---------------------------------------------------------------------------
__global__ __launch_bounds__(256) void kv_z_kernel(
    const __bf16* __restrict__ Kb, const __bf16* __restrict__ Vb,
    float* __restrict__ P)
{
    __shared__ __attribute__((aligned(16))) __bf16 Kt[64 * 36]; // [d][tok]
    __shared__ __attribute__((aligned(16))) __bf16 Vt[64 * 36]; // [e][tok]
    __shared__ float zs[64];
    const int tid = threadIdx.x, wave = tid >> 6, lane = tid & 63;
    const int bh = blockIdx.x, b = bh >> 4, h = bh & 15;
    const int split = blockIdx.y;
    const int n0 = split * (SEQ / NSPLIT);
    const int dg = (tid & 15) * 4;     // 4 consecutive dims per thread
    const int u2 = (tid >> 4) * 2;     // token pair
    const int fr = lane & 15, fk = (lane >> 4) * 8;
    const __bf16* Kp = Kb + ((size_t)b * SEQ + n0) * DIMC + h * HD;
    const __bf16* Vp = Vb + ((size_t)b * SEQ + n0) * DIMC + h * HD;

    if (tid < 64) zs[tid] = 0.0f;
    f32x4 acc[4] = {};
    float zp[4] = {};

    for (int c = 0; c < SEQ / NSPLIT; c += 32) {
        bf16x4 ka = *(const bf16x4*)(Kp + (size_t)(c + u2) * DIMC + dg);
        bf16x4 kb = *(const bf16x4*)(Kp + (size_t)(c + u2 + 1) * DIMC + dg);
        bf16x4 va = *(const bf16x4*)(Vp + (size_t)(c + u2) * DIMC + dg);
        bf16x4 vb = *(const bf16x4*)(Vp + (size_t)(c + u2 + 1) * DIMC + dg);
        __syncthreads();
        #pragma unroll
        for (int q = 0; q < 4; ++q) {
            zp[q] += (float)ka[q] + (float)kb[q];
            *(bf16x2*)(Kt + (dg + q) * 36 + u2) = bf16x2{ka[q], kb[q]};
            *(bf16x2*)(Vt + (dg + q) * 36 + u2) = bf16x2{va[q], vb[q]};
        }
        __syncthreads();

        const __bf16* ar = Kt + (wave * 16 + fr) * 36 + fk;
        bf16x4 alo = *(const bf16x4*)ar, ahi = *(const bf16x4*)(ar + 4);
        bf16x8 af = {alo[0],alo[1],alo[2],alo[3],ahi[0],ahi[1],ahi[2],ahi[3]};
        #pragma unroll
        for (int j = 0; j < 4; ++j) {
            const __bf16* br = Vt + (j * 16 + fr) * 36 + fk;
            bf16x4 blo = *(const bf16x4*)br, bhi = *(const bf16x4*)(br + 4);
            bf16x8 bf = {blo[0],blo[1],blo[2],blo[3],bhi[0],bhi[1],bhi[2],bhi[3]};
            acc[j] = __builtin_amdgcn_mfma_f32_16x16x32_bf16(af, bf, acc[j], 0, 0, 0);
        }
    }

    #pragma unroll
    for (int q = 0; q < 4; ++q) atomicAdd(&zs[dg + q], zp[q]);
    __syncthreads();

    float* KVp = P + (size_t)split * PELEMS + bh * 4096;
    const int col_l = lane & 15, quad = lane >> 4;
    #pragma unroll
    for (int j = 0; j < 4; ++j)
        #pragma unroll
        for (int r = 0; r < 4; ++r)
            KVp[(wave * 16 + quad * 4 + r) * 64 + j * 16 + col_l] = acc[j][r];
    if (tid < 64)
        P[(size_t)split * PELEMS + 64 * 64 * 64 + bh * 64 + tid] = zs[tid];
}

// sum NSPLIT partials -> final KV+Z (contiguous PELEMS floats)
__global__ __launch_bounds__(256) void reduce_partials(
    const float* __restrict__ P, float* __restrict__ F)
{
    const int i = blockIdx.x * 256 + threadIdx.x;
    if (i < PELEMS) {
        float s = 0.0f;
        #pragma unroll
        for (int sp = 0; sp < NSPLIT; ++sp) s += P[(size_t)sp * PELEMS + i];
        F[i] = s;
    }
}

// ---------------------------------------------------------------------------
// Per (b,h, 32-token chunk): out[n,e] = (sum_d Q[n,d]*KV[d,e]) / (Q[n]·Z + eps)
// ---------------------------------------------------------------------------
__global__ __launch_bounds__(256) void attn_apply(
    const __bf16* __restrict__ Qb, const float* __restrict__ KV,
    const float* __restrict__ Z, __bf16* __restrict__ Ab)
{
    __shared__ __align__(16) float KVs[64][64];
    __shared__ __align__(16) float Qs[32][64];
    __shared__ float Zs[64];
    __shared__ float rnorm[32];
    const int tid = threadIdx.x;
    const int bh = blockIdx.y;
    const int b = bh >> 4, h = bh & 15;
    const int n0 = blockIdx.x * 32;

    const float* KVp = KV + (size_t)bh * HD * HD;
    #pragma unroll
    for (int r = 0; r < 4; ++r) {
        const int idx = (r * 256 + tid) * 4;
        *(float4*)&((float*)KVs)[idx] = *(const float4*)(KVp + idx);
    }
    const __bf16* Qp = Qb + ((size_t)(b * SEQ + n0)) * DIMC + h * HD;
    {
        const int tok = tid >> 3, col = (tid & 7) * 8;
        bf16x8 q8 = *(const bf16x8*)(Qp + (size_t)tok * DIMC + col);
        #pragma unroll
        for (int q = 0; q < 8; ++q) Qs[tok][col + q] = (float)q8[q];
    }
    if (tid < 64) Zs[tid] = Z[bh * HD + tid];
    __syncthreads();

    if (tid < 32) {
        float s = 0.0f;
        #pragma unroll
        for (int d = 0; d < 64; ++d) s += Qs[tid][d] * Zs[d];
        rnorm[tid] = 1.0f / (s + EPS);
    }
    __syncthreads();

    const int trow = tid >> 3;
    const int e0 = (tid & 7) * 8;
    float out[8] = {};
    #pragma unroll
    for (int d = 0; d < 64; ++d) {
        const float q = Qs[trow][d];
        #pragma unroll
        for (int j = 0; j < 8; ++j) out[j] = fmaf(q, KVs[d][e0 + j], out[j]);
    }
    const float rn = rnorm[trow];
    __bf16* Op = Ab + ((size_t)(b * SEQ + n0 + trow)) * DIMC + h * HD + e0;
    bf16x8 o;
    #pragma unroll
    for (int j = 0; j < 8; ++j) o[j] = (__bf16)(out[j] * rn);
    *(bf16x8*)Op = o;
}

extern "C" void kernel_launch(void* const* d_in, const int* in_sizes, int n_in,
                              void* d_out, int out_size, void* d_ws, size_t ws_size,
                              hipStream_t stream) {
    const float* x  = (const float*)d_in[0];
    const float* Wq = (const float*)d_in[1];
    const float* bq = (const float*)d_in[2];
    const float* Wk = (const float*)d_in[3];
    const float* bk = (const float*)d_in[4];
    const float* Wv = (const float*)d_in[5];
    const float* bv = (const float*)d_in[6];
    const float* Wo = (const float*)d_in[7];
    const float* bo = (const float*)d_in[8];
    float* out = (float*)d_out;

    const size_t big = (size_t)MTOT * DIMC;     // 16,777,216 elems
    const size_t wsz = (size_t)DIMC * DIMC;     // 1,048,576 elems
    __bf16* wsp = (__bf16*)d_ws;
    __bf16* xb  = wsp;
    __bf16* Wqb = xb + big;
    __bf16* Wkb = Wqb + wsz;
    __bf16* Wvb = Wkb + wsz;
    __bf16* Wob = Wvb + wsz;
    __bf16* Qb  = Wob + wsz;
    __bf16* Kb  = Qb + big;
    __bf16* Vb  = Kb + big;
    __bf16* Ab  = xb;                            // alias: x dead after QKV
    float*  P   = (float*)(Vb + big);            // NSPLIT * PELEMS partials
    float*  F   = P + (size_t)NSPLIT * PELEMS;
    float*  KV  = F;
    float*  Z   = F + 64 * 64 * 64;

    const size_t ntot = big + 4 * wsz;           // 20,971,520 elems
    cvt_all<<<dim3((int)(ntot / 1024)), 256, 0, stream>>>(
        x, Wq, Wk, Wv, Wo, xb, Wqb, Wkb, Wvb, Wob);

    gemm_qkv<<<dim3(256), 512, 0, stream>>>(
        xb, Wqb, Wkb, Wvb, bq, bk, bv, Qb, Kb, Vb);

    kv_z_kernel<<<dim3(BATCH * NH, NSPLIT), 256, 0, stream>>>(Kb, Vb, P);
    reduce_partials<<<dim3((PELEMS + 255) / 256), 256, 0, stream>>>(P, F);
    attn_apply<<<dim3(SEQ / 32, BATCH * NH), 256, 0, stream>>>(Qb, KV, Z, Ab);

    gemm_out<<<dim3(256), 512, 0, stream>>>(Ab, Wob, bo, out);
}

// Round 4
// 342.397 us; speedup vs baseline: 1.0831x; 1.0831x over previous
//
#include <hip/hip_runtime.h>
#include <math.h>

#define DIMC 1024
#define SEQ 4096
#define BATCH 4
#define NH 16
#define HD 64
#define MTOT (BATCH * SEQ)      // 16384 rows
#define NSPLIT 8
#define PELEMS (64 * 64 * 64 + 64 * 64)   // KV partial + Z partial per split
#define EPS 1e-6f
#define NKT (DIMC / 64)         // 16 K-tiles of 64

typedef __bf16 bf16x8 __attribute__((ext_vector_type(8)));
typedef __bf16 bf16x4 __attribute__((ext_vector_type(4)));
typedef __bf16 bf16x2 __attribute__((ext_vector_type(2)));
typedef float  f32x4  __attribute__((ext_vector_type(4)));

#define MFMA16 __builtin_amdgcn_mfma_f32_16x16x32_bf16

__device__ __forceinline__ float phi_f(float x) {
    return x > 0.0f ? x + 1.0f : __expf(x);   // elu(x)+1
}

// ---------------------------------------------------------------------------
// One-shot fp32->bf16 conversion of x + all 4 weight matrices.
// ---------------------------------------------------------------------------
__global__ __launch_bounds__(256) void cvt_all(
    const float* __restrict__ x,
    const float* __restrict__ Wq, const float* __restrict__ Wk,
    const float* __restrict__ Wv, const float* __restrict__ Wo,
    __bf16* __restrict__ xb,
    __bf16* __restrict__ Wqb, __bf16* __restrict__ Wkb,
    __bf16* __restrict__ Wvb, __bf16* __restrict__ Wob)
{
    const size_t big = (size_t)MTOT * DIMC;
    const size_t wsz = (size_t)DIMC * DIMC;
    size_t i = ((size_t)blockIdx.x * 256 + threadIdx.x) * 4;
    const float* src; __bf16* dst; size_t off;
    if (i < big) { src = x; dst = xb; off = i; }
    else {
        size_t j = i - big;
        int w = (int)(j >> 20);            // /wsz (2^20)
        off = j & (wsz - 1);
        switch (w) {
            case 0: src = Wq; dst = Wqb; break;
            case 1: src = Wk; dst = Wkb; break;
            case 2: src = Wv; dst = Wvb; break;
            default: src = Wo; dst = Wob; break;
        }
    }
    float4 v = *(const float4*)(src + off);
    bf16x4 o = { (__bf16)v.x, (__bf16)v.y, (__bf16)v.z, (__bf16)v.w };
    *(bf16x4*)(dst + off) = o;
}

// ---------------------------------------------------------------------------
// 256x256 8-wave BK=64 GEMM tile, 8-phase schedule, counted vmcnt
// (T2+T3+T4+T5). R3 isolated: the R1 grid (one matrix per block, matrix-major
// per-XCD ordering) is the best-known config — the persistent 48-tile fusion
// REGRESSED (FETCH +25 MB from A-panel L2 misses at matrix boundaries +
// epilogue-store drains inside the counted-vmcnt window). Reverted to R1
// structure; the one R3-proven win kept is the j-INNER epilogue store order
// (WRITE_SIZE 200 -> 114.7 MB, partial-line evictions eliminated).
//
// LDS: 2 buf x {A,B} x 2 row-halves x [128][64] bf16 = 128 KiB.
// Swizzle: linear global_load_lds dest + pre-swizzled GLOBAL source column
// block (blk ^= row&7) + same XOR on ds_read (rule #21). R1 measured:
// SQ_LDS_BANK_CONFLICT 1.26e7 -> 0.
// ---------------------------------------------------------------------------
template<int OUT_BF16>
__device__ __forceinline__ void gemm_tile256(
    const __bf16* __restrict__ X, const __bf16* __restrict__ W,
    const float* __restrict__ bias, void* __restrict__ Yv,
    int m0, int n0, int do_phi)
{
    __shared__ __attribute__((aligned(16))) __bf16 lds[65536]; // 128 KiB
    const int tid  = threadIdx.x;
    const int wave = tid >> 6, lane = tid & 63;
    const int wm = wave >> 2, wn = wave & 3;          // 2 x 4 wave grid
    const int fr = lane & 15, fkb = lane >> 4;        // fragment row / k-block
    const int fsw = fr & 7;                           // read-side XOR swizzle
    const int srow = lane >> 3;                       // staging row in 8-group
    const int sblk = (lane & 7) ^ srow;               // pre-swizzled src block

    const __bf16* Asrc = X + (size_t)(m0 + wave * 8 + srow) * DIMC + sblk * 8;
    const __bf16* Bsrc = W + (size_t)(n0 + wave * 8 + srow) * DIMC + sblk * 8;
    __bf16* lw = lds + wave * 512;   // wave's 8-row slice in each 64-row block

    auto stage = [&](int isB, int h, int kblk, int bb) {
        const __bf16* s = (isB ? Bsrc : Asrc)
                          + (size_t)(h * 128) * DIMC + (size_t)kblk * 64;
        __bf16* d = lw + bb * 32768 + isB * 16384 + h * 8192;
        #pragma unroll
        for (int g = 0; g < 2; ++g)
            __builtin_amdgcn_global_load_lds(
                (const __attribute__((address_space(1))) void*)(s + (size_t)g * 64 * DIMC),
                (__attribute__((address_space(3))) void*)(d + g * 4096),
                16, 0, 0);
    };
    // A frag: rows wm*128 + i*16 + fr, k = ks*32 + fkb*8 (block XOR-swizzled)
    auto lda = [&](int bb, int i, int ks) -> bf16x8 {
        return *(const bf16x8*)(lds + bb * 32768 + wm * 8192
                 + (i * 16 + fr) * 64 + (((ks * 4 + fkb) ^ fsw) * 8));
    };
    // B frag: rows wn*64 + j*16 + fr  (half = wn>>1, local row = (wn&1)*64+..)
    auto ldb = [&](int bb, int j, int ks) -> bf16x8 {
        return *(const bf16x8*)(lds + bb * 32768 + 16384 + (wn >> 1) * 8192
                 + ((wn & 1) * 64 + j * 16 + fr) * 64 + (((ks * 4 + fkb) ^ fsw) * 8));
    };

    f32x4 acc[8][4] = {};
    bf16x8 a[4][2], b[4][2];

    // prologue: tile0 {B0,B1,A0,A1} + tile1 {B0,B1,A0}; A1(1) issued in ph1(0)
    stage(1, 0, 0, 0); stage(1, 1, 0, 0);
    stage(0, 0, 0, 0); stage(0, 1, 0, 0);
    stage(1, 0, 1, 1); stage(1, 1, 1, 1);
    stage(0, 0, 1, 1);
    asm volatile("s_waitcnt vmcnt(6)" ::: "memory");   // tile 0 resident
    __builtin_amdgcn_s_barrier();

    #pragma unroll 2
    for (int t = 0; t < NKT; ++t) {
        const int buf = t & 1;
        // ---- phase 1: A frags 0-3, B frags 0-1; stage A-h1(t+1)
        #pragma unroll
        for (int i = 0; i < 4; ++i)
            #pragma unroll
            for (int ks = 0; ks < 2; ++ks) a[i][ks] = lda(buf, i, ks);
        #pragma unroll
        for (int j = 0; j < 2; ++j)
            #pragma unroll
            for (int ks = 0; ks < 2; ++ks) b[j][ks] = ldb(buf, j, ks);
        if (t + 1 < NKT) stage(0, 1, t + 1, buf ^ 1);
        __builtin_amdgcn_s_barrier();
        asm volatile("s_waitcnt lgkmcnt(0)" ::: "memory");
        __builtin_amdgcn_s_setprio(1);
        #pragma unroll
        for (int i = 0; i < 4; ++i)
            #pragma unroll
            for (int j = 0; j < 2; ++j)
                #pragma unroll
                for (int ks = 0; ks < 2; ++ks)
                    acc[i][j] = MFMA16(a[i][ks], b[j][ks], acc[i][j], 0, 0, 0);
        __builtin_amdgcn_s_setprio(0);
        __builtin_amdgcn_s_barrier();
        // ---- phase 2: B frags 2-3
        #pragma unroll
        for (int j = 2; j < 4; ++j)
            #pragma unroll
            for (int ks = 0; ks < 2; ++ks) b[j][ks] = ldb(buf, j, ks);
        __builtin_amdgcn_s_barrier();
        asm volatile("s_waitcnt lgkmcnt(0)" ::: "memory");
        __builtin_amdgcn_s_setprio(1);
        #pragma unroll
        for (int i = 0; i < 4; ++i)
            #pragma unroll
            for (int j = 2; j < 4; ++j)
                #pragma unroll
                for (int ks = 0; ks < 2; ++ks)
                    acc[i][j] = MFMA16(a[i][ks], b[j][ks], acc[i][j], 0, 0, 0);
        __builtin_amdgcn_s_setprio(0);
        __builtin_amdgcn_s_barrier();
        // ---- phase 3: A frags 4-7; stage B-h0(t+2)
        #pragma unroll
        for (int i = 0; i < 4; ++i)
            #pragma unroll
            for (int ks = 0; ks < 2; ++ks) a[i][ks] = lda(buf, i + 4, ks);
        if (t + 2 < NKT) stage(1, 0, t + 2, buf);
        __builtin_amdgcn_s_barrier();
        asm volatile("s_waitcnt lgkmcnt(0)" ::: "memory");
        __builtin_amdgcn_s_setprio(1);
        #pragma unroll
        for (int i = 0; i < 4; ++i)
            #pragma unroll
            for (int j = 2; j < 4; ++j)
                #pragma unroll
                for (int ks = 0; ks < 2; ++ks)
                    acc[i + 4][j] = MFMA16(a[i][ks], b[j][ks], acc[i + 4][j], 0, 0, 0);
        __builtin_amdgcn_s_setprio(0);
        __builtin_amdgcn_s_barrier();
        // ---- phase 4: stage B-h1(t+2), A-h0(t+2); reg-only MFMA; counted vmcnt
        if (t + 2 < NKT) {
            stage(1, 1, t + 2, buf);
            stage(0, 0, t + 2, buf);
        }
        __builtin_amdgcn_s_setprio(1);
        #pragma unroll
        for (int i = 0; i < 4; ++i)
            #pragma unroll
            for (int j = 0; j < 2; ++j)
                #pragma unroll
                for (int ks = 0; ks < 2; ++ks)
                    acc[i + 4][j] = MFMA16(a[i][ks], b[j][ks], acc[i + 4][j], 0, 0, 0);
        __builtin_amdgcn_s_setprio(0);
        if (t < NKT - 2)       asm volatile("s_waitcnt vmcnt(6)" ::: "memory");
        else if (t == NKT - 2) asm volatile("s_waitcnt vmcnt(0)" ::: "memory");
        __builtin_amdgcn_s_barrier();
    }

    // epilogue (outside loop): C/D layout col=lane&15, row=(lane>>4)*4+reg.
    // j-INNER store order: each 16-lane quad closes its 128B line in 4
    // consecutive stores (R3-measured: WRITE_SIZE 200 -> 114.7 MB).
    const int col_l = lane & 15, quad = lane >> 4;
    const int cbase = n0 + wn * 64 + col_l;
    float bb4[4];
    #pragma unroll
    for (int j = 0; j < 4; ++j) bb4[j] = bias[cbase + j * 16];
    #pragma unroll
    for (int i = 0; i < 8; ++i) {
        #pragma unroll
        for (int r = 0; r < 4; ++r) {
            const size_t grow = (size_t)(m0 + wm * 128 + i * 16 + quad * 4 + r) * DIMC;
            #pragma unroll
            for (int j = 0; j < 4; ++j) {
                float v = acc[i][j][r] + bb4[j];
                if (do_phi) v = phi_f(v);
                if (OUT_BF16)
                    ((__bf16*)Yv)[grow + cbase + j * 16] = (__bf16)v;
                else
                    ((float*)Yv)[grow + cbase + j * 16] = v;
            }
        }
    }
}

// ---------------------------------------------------------------------------
// Fused Q/K/V projection, R1 grid: 768 blocks = 8 XCD x 3 mat x 8 m x 4 n.
// Matrix-major per-XCD ordering keeps W_mat (2 MB) L2-hot; X panels stream.
// ---------------------------------------------------------------------------
__global__ __launch_bounds__(512, 2) void gemm_qkv(
    const __bf16* __restrict__ X,
    const __bf16* __restrict__ Wq, const __bf16* __restrict__ Wk,
    const __bf16* __restrict__ Wv,
    const float* __restrict__ bq, const float* __restrict__ bk,
    const float* __restrict__ bv,
    __bf16* __restrict__ Q, __bf16* __restrict__ K, __bf16* __restrict__ V)
{
    const int l = blockIdx.x;
    const int xcd = l & 7, s = l >> 3;          // s in [0,96)
    const int mat = s >> 5;                     // 32 blocks per matrix per XCD
    const int t = s & 31;
    const int nb = t & 3;                       // fastest: n-block
    const int m_idx = xcd * 8 + (t >> 2);       // 8 m-panels per XCD
    const __bf16* W = (mat == 0) ? Wq : (mat == 1) ? Wk : Wv;
    const float* bias = (mat == 0) ? bq : (mat == 1) ? bk : bv;
    __bf16* Y = (mat == 0) ? Q : (mat == 1) ? K : V;
    gemm_tile256<1>(X, W, bias, (void*)Y, m_idx * 256, nb * 256, mat != 2);
}

// ---------------------------------------------------------------------------
// Output projection: out = A @ Wo^T + bo (fp32 out). 256 blocks = 1/CU.
// ---------------------------------------------------------------------------
__global__ __launch_bounds__(512, 2) void gemm_out(
    const __bf16* __restrict__ A, const __bf16* __restrict__ Wo,
    const float* __restrict__ bo, float* __restrict__ out)
{
    const int l = blockIdx.x;
    const int xcd = l & 7, s = l >> 3;          // s in [0,32)
    const int m_idx = xcd * 8 + (s >> 2);
    const int nb = s & 3;
    gemm_tile256<0>(A, Wo, bo, (void*)out, m_idx * 256, nb * 256, 0);
}

// ---------------------------------------------------------------------------
// Per (b,h,split): partial KV[d][e] = sum_n K[n,d]*V[n,e], partial Z[d].
// R4: double-buffered LDS tiles -> ONE barrier per 32-token chunk (was two),
// with next chunk's global loads issued before the barrier so HBM latency
// hides under the transpose-write + MFMA of the current chunk.
// Hazard audit: writes(c) target buf[c&1]; conflicting reads were reads(c-2),
// which completed before their wave passed barrier(c-1) (compiler waitcnt
// before MFMA consumption). One barrier per iter is sufficient.
// ---------------------------------------------------------------------------
__global__ __launch_bounds__(256) void kv_z_kernel(
    const __bf16* __restrict__ Kb, const __bf16* __restrict__ Vb,
    float* __restrict__ P)
{
    __shared__ __attribute__((aligned(16))) __bf16 Kt[2][64 * 36]; // [d][tok]
    __shared__ __attribute__((aligned(16))) __bf16 Vt[2][64 * 36]; // [e][tok]
    __shared__ float zs[64];
    const int tid = threadIdx.x, wave = tid >> 6, lane = tid & 63;
    const int bh = blockIdx.x, b = bh >> 4, h = bh & 15;
    const int split = blockIdx.y;
    const int n0 = split * (SEQ / NSPLIT);
    const int dg = (tid & 15) * 4;     // 4 consecutive dims per thread
    const int u2 = (tid >> 4) * 2;     // token pair
    const int fr = lane & 15, fk = (lane >> 4) * 8;
    const __bf16* Kp = Kb + ((size_t)b * SEQ + n0) * DIMC + h * HD;
    const __bf16* Vp = Vb + ((size_t)b * SEQ + n0) * DIMC + h * HD;
    constexpr int CH = (SEQ / NSPLIT) / 32;   // 16 chunks

    if (tid < 64) zs[tid] = 0.0f;
    f32x4 acc[4] = {};
    float zp[4] = {};

    auto ldc = [&](int c, bf16x4& ka, bf16x4& kb, bf16x4& va, bf16x4& vb) {
        ka = *(const bf16x4*)(Kp + (size_t)(c * 32 + u2) * DIMC + dg);
        kb = *(const bf16x4*)(Kp + (size_t)(c * 32 + u2 + 1) * DIMC + dg);
        va = *(const bf16x4*)(Vp + (size_t)(c * 32 + u2) * DIMC + dg);
        vb = *(const bf16x4*)(Vp + (size_t)(c * 32 + u2 + 1) * DIMC + dg);
    };

    bf16x4 ka, kb, va, vb;
    ldc(0, ka, kb, va, vb);

    for (int c = 0; c < CH; ++c) {
        const int p = c & 1;
        #pragma unroll
        for (int q = 0; q < 4; ++q) {
            zp[q] += (float)ka[q] + (float)kb[q];
            *(bf16x2*)(Kt[p] + (dg + q) * 36 + u2) = bf16x2{ka[q], kb[q]};
            *(bf16x2*)(Vt[p] + (dg + q) * 36 + u2) = bf16x2{va[q], vb[q]};
        }
        bf16x4 nka, nkb, nva, nvb;
        if (c + 1 < CH) ldc(c + 1, nka, nkb, nva, nvb);
        __syncthreads();

        const __bf16* ar = Kt[p] + (wave * 16 + fr) * 36 + fk;
        bf16x4 alo = *(const bf16x4*)ar, ahi = *(const bf16x4*)(ar + 4);
        bf16x8 af = {alo[0],alo[1],alo[2],alo[3],ahi[0],ahi[1],ahi[2],ahi[3]};
        #pragma unroll
        for (int j = 0; j < 4; ++j) {
            const __bf16* br = Vt[p] + (j * 16 + fr) * 36 + fk;
            bf16x4 blo = *(const bf16x4*)br, bhi = *(const bf16x4*)(br + 4);
            bf16x8 bf = {blo[0],blo[1],blo[2],blo[3],bhi[0],bhi[1],bhi[2],bhi[3]};
            acc[j] = __builtin_amdgcn_mfma_f32_16x16x32_bf16(af, bf, acc[j], 0, 0, 0);
        }
        ka = nka; kb = nkb; va = nva; vb = nvb;
    }

    #pragma unroll
    for (int q = 0; q < 4; ++q) atomicAdd(&zs[dg + q], zp[q]);
    __syncthreads();

    float* KVp = P + (size_t)split * PELEMS + bh * 4096;
    const int col_l = lane & 15, quad = lane >> 4;
    #pragma unroll
    for (int j = 0; j < 4; ++j)
        #pragma unroll
        for (int r = 0; r < 4; ++r)
            KVp[(wave * 16 + quad * 4 + r) * 64 + j * 16 + col_l] = acc[j][r];
    if (tid < 64)
        P[(size_t)split * PELEMS + 64 * 64 * 64 + bh * 64 + tid] = zs[tid];
}

// sum NSPLIT partials -> final KV+Z (contiguous PELEMS floats)
__global__ __launch_bounds__(256) void reduce_partials(
    const float* __restrict__ P, float* __restrict__ F)
{
    const int i = blockIdx.x * 256 + threadIdx.x;
    if (i < PELEMS) {
        float s = 0.0f;
        #pragma unroll
        for (int sp = 0; sp < NSPLIT; ++sp) s += P[(size_t)sp * PELEMS + i];
        F[i] = s;
    }
}

// ---------------------------------------------------------------------------
// Per (b,h, 32-token chunk): out[n,e] = (sum_d Q[n,d]*KV[d,e]) / (Q[n]·Z + eps)
// ---------------------------------------------------------------------------
__global__ __launch_bounds__(256) void attn_apply(
    const __bf16* __restrict__ Qb, const float* __restrict__ KV,
    const float* __restrict__ Z, __bf16* __restrict__ Ab)
{
    __shared__ __align__(16) float KVs[64][64];
    __shared__ __align__(16) float Qs[32][64];
    __shared__ float Zs[64];
    __shared__ float rnorm[32];
    const int tid = threadIdx.x;
    const int bh = blockIdx.y;
    const int b = bh >> 4, h = bh & 15;
    const int n0 = blockIdx.x * 32;

    const float* KVp = KV + (size_t)bh * HD * HD;
    #pragma unroll
    for (int r = 0; r < 4; ++r) {
        const int idx = (r * 256 + tid) * 4;
        *(float4*)&((float*)KVs)[idx] = *(const float4*)(KVp + idx);
    }
    const __bf16* Qp = Qb + ((size_t)(b * SEQ + n0)) * DIMC + h * HD;
    {
        const int tok = tid >> 3, col = (tid & 7) * 8;
        bf16x8 q8 = *(const bf16x8*)(Qp + (size_t)tok * DIMC + col);
        #pragma unroll
        for (int q = 0; q < 8; ++q) Qs[tok][col + q] = (float)q8[q];
    }
    if (tid < 64) Zs[tid] = Z[bh * HD + tid];
    __syncthreads();

    if (tid < 32) {
        float s = 0.0f;
        #pragma unroll
        for (int d = 0; d < 64; ++d) s += Qs[tid][d] * Zs[d];
        rnorm[tid] = 1.0f / (s + EPS);
    }
    __syncthreads();

    const int trow = tid >> 3;
    const int e0 = (tid & 7) * 8;
    float out[8] = {};
    #pragma unroll
    for (int d = 0; d < 64; ++d) {
        const float q = Qs[trow][d];
        #pragma unroll
        for (int j = 0; j < 8; ++j) out[j] = fmaf(q, KVs[d][e0 + j], out[j]);
    }
    const float rn = rnorm[trow];
    __bf16* Op = Ab + ((size_t)(b * SEQ + n0 + trow)) * DIMC + h * HD + e0;
    bf16x8 o;
    #pragma unroll
    for (int j = 0; j < 8; ++j) o[j] = (__bf16)(out[j] * rn);
    *(bf16x8*)Op = o;
}

extern "C" void kernel_launch(void* const* d_in, const int* in_sizes, int n_in,
                              void* d_out, int out_size, void* d_ws, size_t ws_size,
                              hipStream_t stream) {
    const float* x  = (const float*)d_in[0];
    const float* Wq = (const float*)d_in[1];
    const float* bq = (const float*)d_in[2];
    const float* Wk = (const float*)d_in[3];
    const float* bk = (const float*)d_in[4];
    const float* Wv = (const float*)d_in[5];
    const float* bv = (const float*)d_in[6];
    const float* Wo = (const float*)d_in[7];
    const float* bo = (const float*)d_in[8];
    float* out = (float*)d_out;

    const size_t big = (size_t)MTOT * DIMC;     // 16,777,216 elems
    const size_t wsz = (size_t)DIMC * DIMC;     // 1,048,576 elems
    __bf16* wsp = (__bf16*)d_ws;
    __bf16* xb  = wsp;
    __bf16* Wqb = xb + big;
    __bf16* Wkb = Wqb + wsz;
    __bf16* Wvb = Wkb + wsz;
    __bf16* Wob = Wvb + wsz;
    __bf16* Qb  = Wob + wsz;
    __bf16* Kb  = Qb + big;
    __bf16* Vb  = Kb + big;
    __bf16* Ab  = xb;                            // alias: x dead after QKV
    float*  P   = (float*)(Vb + big);            // NSPLIT * PELEMS partials
    float*  F   = P + (size_t)NSPLIT * PELEMS;
    float*  KV  = F;
    float*  Z   = F + 64 * 64 * 64;

    const size_t ntot = big + 4 * wsz;           // 20,971,520 elems
    cvt_all<<<dim3((int)(ntot / 1024)), 256, 0, stream>>>(
        x, Wq, Wk, Wv, Wo, xb, Wqb, Wkb, Wvb, Wob);

    gemm_qkv<<<dim3(768), 512, 0, stream>>>(
        xb, Wqb, Wkb, Wvb, bq, bk, bv, Qb, Kb, Vb);

    kv_z_kernel<<<dim3(BATCH * NH, NSPLIT), 256, 0, stream>>>(Kb, Vb, P);
    reduce_partials<<<dim3((PELEMS + 255) / 256), 256, 0, stream>>>(P, F);
    attn_apply<<<dim3(SEQ / 32, BATCH * NH), 256, 0, stream>>>(Qb, KV, Z, Ab);

    gemm_out<<<dim3(256), 512, 0, stream>>>(Ab, Wob, bo, out);
}